// Round 1
// 807.208 us; speedup vs baseline: 1.1559x; 1.1559x over previous
//
#include <hip/hip_runtime.h>

// ---------------------------------------------------------------------------
// GQA attention block: QKV proj -> RoPE -> causal GQA flash attention -> out proj
// B=2 S=2048 D=4096 NH=32 NKV=8 HD=128 (QKV_DIM=6144)
// R4: GEMMs replaced with the 256x256 8-phase template (plain-HIP port of the
//     m201/HipKittens schedule): BK=64, 8 waves (2x4), 128KiB double-buffered
//     dynamic LDS, st_16x32 XOR swizzle (write via pre-swizzled global source,
//     read via swizzled ds_read addr), counted vmcnt(6) across raw s_barriers
//     (never drained in the main loop), s_setprio(1) around each 16-MFMA
//     cluster, bijective XCD-aware blockIdx swizzle (grids are %8==0).
// ---------------------------------------------------------------------------

typedef __bf16 bf16;
typedef bf16 bf16x8 __attribute__((ext_vector_type(8)));
typedef bf16 bf16x4 __attribute__((ext_vector_type(4)));
typedef float f32x4 __attribute__((ext_vector_type(4)));
typedef unsigned int u32;
typedef u32 u32x4 __attribute__((ext_vector_type(4)));

#define B_ 2
#define S_ 2048
#define DM 4096
#define NH 32
#define NKV 8
#define HD 128
#define QKV_DIM 6144

typedef __attribute__((address_space(3))) void lds_void;
typedef const __attribute__((address_space(1))) void glb_void;

__device__ __forceinline__ void gld_lds16(const bf16* g, bf16* l) {
  __builtin_amdgcn_global_load_lds((glb_void*)g, (lds_void*)l, 16, 0, 0);
}

__device__ __forceinline__ u32 bf16bits(float x) {
  union { bf16 h; unsigned short s; } u;
  u.h = (bf16)x;
  return (u32)u.s;
}

// ---------------- cast fp32 -> bf16 (hidden states) ----------------
__global__ __launch_bounds__(256) void cast_f32_bf16(const float* __restrict__ src,
                                                     bf16* __restrict__ dst, int n) {
  int i = (blockIdx.x * 256 + threadIdx.x) * 4;
  float4 v = *(const float4*)(src + i);
  bf16x4 o;
  o[0] = (bf16)v.x; o[1] = (bf16)v.y; o[2] = (bf16)v.z; o[3] = (bf16)v.w;
  *(bf16x4*)(dst + i) = o;
}

// ---------------- transpose + cast weights: W[K][N] f32 -> Wt[N][K] bf16 ----
__global__ __launch_bounds__(256) void transpose_cast_w(const float* __restrict__ W,
                                                        bf16* __restrict__ Wt,
                                                        int K, int N) {
  __shared__ float tile[64][65];
  const int n0 = blockIdx.x * 64, k0 = blockIdx.y * 64;
  const int t = threadIdx.x, j = t & 63, i0 = t >> 6;
  for (int p = 0; p < 16; ++p) {
    int i = i0 + p * 4;
    tile[i][j] = W[(size_t)(k0 + i) * N + n0 + j];
  }
  __syncthreads();
  for (int p = 0; p < 16; ++p) {
    int n = i0 + p * 4;
    Wt[(size_t)(n0 + n) * K + k0 + j] = (bf16)tile[j][n];
  }
}

// ---------------- transpose V out of qkv: v_t[b][kv][d][s] ----------------
__global__ __launch_bounds__(256) void transpose_v(const bf16* __restrict__ qkv,
                                                   bf16* __restrict__ v_t) {
  __shared__ bf16 tile[64][65];
  const int s0 = blockIdx.x * 64;
  const int d0 = blockIdx.y * 64;
  const int bk = blockIdx.z;            // b*8+kv
  const int b = bk >> 3, kv = bk & 7;
  const int t = threadIdx.x, j = t & 63, i0 = t >> 6;
  const bf16* src = qkv + (size_t)b * S_ * QKV_DIM + 5120 + kv * HD;  // v offset 5120
  for (int p = 0; p < 16; ++p) {
    int i = i0 + p * 4;
    tile[i][j] = src[(size_t)(s0 + i) * QKV_DIM + d0 + j];
  }
  __syncthreads();
  bf16* dst = v_t + ((size_t)bk * HD + d0) * S_ + s0;
  for (int p = 0; p < 16; ++p) {
    int dd = i0 + p * 4;
    dst[(size_t)dd * S_ + j] = tile[j][dd];
  }
}

// ---------------- RoPE + repack q,k (q pre-scaled by 1/sqrt(HD)) ----------
__global__ __launch_bounds__(128) void rope_kernel(const bf16* __restrict__ qkv,
                                                   const float* __restrict__ cosT,
                                                   const float* __restrict__ sinT,
                                                   bf16* __restrict__ q_r,
                                                   bf16* __restrict__ k_r) {
  const int bs = blockIdx.x;            // b*S + s
  const int b = bs >> 11, s = bs & 2047;
  const int d = threadIdx.x;            // 0..127
  const float cv = cosT[s * HD + d];
  const float sv = sinT[s * HD + d];
  const bf16* row = qkv + (size_t)bs * QKV_DIM;
  const float scale = 0.08838834764831845f;  // 1/sqrt(128)
  for (int h = 0; h < NH; ++h) {
    float x = (float)row[h * HD + d];
    float xr = (d < 64) ? -(float)row[h * HD + d + 64] : (float)row[h * HD + d - 64];
    q_r[(((size_t)(b * NH + h)) * S_ + s) * HD + d] = (bf16)((x * cv + xr * sv) * scale);
  }
  for (int kv = 0; kv < NKV; ++kv) {
    float x = (float)row[DM + kv * HD + d];
    float xr = (d < 64) ? -(float)row[DM + kv * HD + d + 64] : (float)row[DM + kv * HD + d - 64];
    k_r[(((size_t)(b * NKV + kv)) * S_ + s) * HD + d] = (bf16)(x * cv + xr * sv);
  }
}

// ---------------- GEMM: C[M][N] = A[M][K] * Bt[N][K]^T  (256x256 8-phase) ---
// 512 threads = 8 waves (2 Mrows x 4 Ncols), per-wave output 128x64.
// BK=64 as two K-halves; LDS per buffer: A[2 halves][256 rows][32 cols bf16]
// + B same = 64 KiB; double-buffered = 128 KiB (dynamic).
// K-half layout row stride 64 B, swizzled: byte ^= ((byte>>9)&1)<<5
//  (bit 9 == row&8 within a 16-row/1024-B subtile). global_load_lds writes
// linearly (wave base + lane*16), so the *global source* lane address carries
// the inverse swizzle: col-granule = (lane&3) ^ ((lane>>4)&2).
// Staging stream: per tile t, halves {A-k0, B-k0, A-k1, B-k1}; half H=4t+j+7
// is issued at phase j of tile t (7 halves pre-issued in the prologue), so
// vmcnt(6) at each tile boundary leaves exactly 3 half-tiles in flight.
#define BAR() __builtin_amdgcn_s_barrier()
#define LGKM0() asm volatile("s_waitcnt lgkmcnt(0)" ::: "memory")
#define VM6() asm volatile("s_waitcnt vmcnt(6)" ::: "memory")
#define VM0() asm volatile("s_waitcnt vmcnt(0)" ::: "memory")
#define VMNONE() do {} while (0)
#define PRIO1() __builtin_amdgcn_s_setprio(1)
#define PRIO0() __builtin_amdgcn_s_setprio(0)

#define MFMA16(MH)                                                                   \
  do {                                                                               \
    _Pragma("unroll") for (int mm = 0; mm < 4; ++mm) {                               \
      _Pragma("unroll") for (int nn = 0; nn < 4; ++nn) {                             \
        acc[(MH)*4 + mm][nn] = __builtin_amdgcn_mfma_f32_16x16x32_bf16(              \
            af[mm], bfr[nn], acc[(MH)*4 + mm][nn], 0, 0, 0);                         \
      }                                                                              \
    }                                                                                \
  } while (0)

// one K-tile = 4 phases; P = LDS buffer (literal 0/1); VMEND at the last phase
#define TILE4(T, P, VMEND)                                                           \
  do {                                                                               \
    ldA(P, 0, 0); ldB(P, 0);                                                         \
    stage_idx(4 * (T) + 7);                                                          \
    BAR(); LGKM0();                                                                  \
    PRIO1(); MFMA16(0); PRIO0(); BAR();                                              \
    ldA(P, 0, 1);                                                                    \
    stage_idx(4 * (T) + 8);                                                          \
    BAR(); LGKM0();                                                                  \
    PRIO1(); MFMA16(1); PRIO0(); BAR();                                              \
    ldA(P, 1, 0); ldB(P, 1);                                                         \
    stage_idx(4 * (T) + 9);                                                          \
    BAR(); LGKM0();                                                                  \
    PRIO1(); MFMA16(0); PRIO0(); BAR();                                              \
    ldA(P, 1, 1);                                                                    \
    stage_idx(4 * (T) + 10);                                                         \
    BAR(); LGKM0();                                                                  \
    PRIO1(); MFMA16(1); PRIO0();                                                     \
    VMEND; BAR();                                                                    \
  } while (0)

template <bool OUT_BF16>
__global__ __launch_bounds__(512, 2) void gemm256_bt(const bf16* __restrict__ A,
                                                     const bf16* __restrict__ Bt,
                                                     void* __restrict__ Cout,
                                                     int M, int N, int K) {
  extern __shared__ char lds[];
  const int NT = K >> 6;                 // K-tiles of 64 (even; K%128==0 here)

  // bijective XCD swizzle (both grids are multiples of 8)
  const int nwg = gridDim.x;
  const int cpx = nwg >> 3;
  const int wg = (blockIdx.x & 7) * cpx + (blockIdx.x >> 3);
  const int nbx = N >> 8;
  const int bx = wg % nbx, by = wg / nbx;
  const int m0 = by * 256, n0 = bx * 256;

  const int t = threadIdx.x;
  const int w = t >> 6, lane = t & 63;
  const int wr = w >> 2, wc = w & 3;     // wave grid 2 x 4
  const int quad = lane >> 4, c = lane & 15;

  // swizzled ds_read base offsets (bit9 of row*64 == c&8; adds below are all
  // multiples of 1024 so the XOR commutes with them)
  const int aOff = (((wr * 128 + c) * 64 + quad * 16) ^ ((c & 8) << 2));
  const int bOff = (((wc * 64 + c) * 64 + quad * 16) ^ ((c & 8) << 2)) + 32768;

  // staging constants: wave w stages rows 32w..32w+31 of each 256-row K-half,
  // global col-granule pre-swizzled so linear LDS dest lands swizzled data
  const int srow = w * 32 + (lane >> 2);
  const int scol = (((lane & 3) ^ ((lane >> 4) & 2)) << 3);  // elements
  const bf16* Abase = A + (size_t)(m0 + srow) * K + scol;
  const bf16* Bbase = Bt + (size_t)(n0 + srow) * K + scol;
  const size_t rs16 = (size_t)16 * K;

  auto stage_idx = [&](int H) {
    if (H >= 4 * NT) return;
    const int tS = H >> 2, jS = H & 3;   // jS: 0=A-k0 1=B-k0 2=A-k1 3=B-k1
    const int kh = jS >> 1;
    const int kbase = tS * 64 + kh * 32;
    const int regionOff = ((tS & 1) << 16) + ((jS & 1) << 15) + (kh << 14) + (w << 11);
    const bf16* g = ((jS & 1) ? Bbase : Abase) + kbase;
    char* l = lds + regionOff;           // wave-uniform; HW adds lane*16
    gld_lds16(g, (bf16*)l);
    gld_lds16(g + rs16, (bf16*)(l + 1024));
  };

  bf16x8 af[4], bfr[4];
  auto ldA = [&](int P, int s, int mh) {
    const char* base = lds + P * 65536 + s * 16384 + mh * 4096 + aOff;
    af[0] = *(const bf16x8*)(base);
    af[1] = *(const bf16x8*)(base + 1024);
    af[2] = *(const bf16x8*)(base + 2048);
    af[3] = *(const bf16x8*)(base + 3072);
  };
  auto ldB = [&](int P, int s) {
    const char* base = lds + P * 65536 + s * 16384 + bOff;
    bfr[0] = *(const bf16x8*)(base);
    bfr[1] = *(const bf16x8*)(base + 1024);
    bfr[2] = *(const bf16x8*)(base + 2048);
    bfr[3] = *(const bf16x8*)(base + 3072);
  };

  f32x4 acc[8][4];
#pragma unroll
  for (int i = 0; i < 8; ++i)
#pragma unroll
    for (int j = 0; j < 4; ++j) acc[i][j] = (f32x4){0.f, 0.f, 0.f, 0.f};

  // prologue: issue tile0's 4 halves + tile1's first 3, wait for tile0 only
#pragma unroll
  for (int hh = 0; hh < 7; ++hh) stage_idx(hh);
  VM6();
  BAR();

  for (int tt = 0; tt < NT - 2; tt += 2) {
    TILE4(tt, 0, VM6());
    TILE4(tt + 1, 1, VM6());
  }
  TILE4(NT - 2, 0, VM0());
  TILE4(NT - 1, 1, VMNONE());

  // epilogue: C write (verified m97 fragment mapping: row=quad*4+r, col=c)
  const int crow = m0 + wr * 128 + quad * 4;
  const int ccol = n0 + wc * 64 + c;
#pragma unroll
  for (int mf = 0; mf < 8; ++mf)
#pragma unroll
    for (int nn = 0; nn < 4; ++nn) {
      const int row = crow + mf * 16;
      const int col = ccol + nn * 16;
      if constexpr (OUT_BF16) {
        bf16* Cp = (bf16*)Cout;
#pragma unroll
        for (int r = 0; r < 4; ++r) Cp[(size_t)(row + r) * N + col] = (bf16)acc[mf][nn][r];
      } else {
        float* Cp = (float*)Cout;
#pragma unroll
        for (int r = 0; r < 4; ++r) Cp[(size_t)(row + r) * N + col] = acc[mf][nn][r];
      }
    }
}

// ---------------- flash attention (causal GQA, transposed-S) ---------------
// grid: (B*NH, S/64). 4 waves/block, wave w owns q rows [q0+16w, q0+16w+16).
// K-chunk = 32 keys. Ks[key][d] (+8 pad), Vs[d][key] (+8 pad).
// S^T = K*Q^T: lane (c,quad) holds 8 scores (2 key-tiles x 4 regs) for the
// single q-row q0+16w+c -> softmax reduces in-register + 2 shfl. P converted
// to MFMA A-layout via 8 bpermutes (packed bf16 pairs), no LDS round-trip.
#define SKS 136
#define SVS 40
__global__ __launch_bounds__(256) void attn_kernel(const bf16* __restrict__ q_r,
                                                   const bf16* __restrict__ k_r,
                                                   const bf16* __restrict__ v_t,
                                                   bf16* __restrict__ attn_out) {
  __shared__ bf16 Ks[32 * SKS];
  __shared__ bf16 Vs[128 * SVS];

  const int bh = blockIdx.x;           // b*NH + h
  const int b = bh >> 5, h = bh & 31;
  const int kv = h >> 2;               // N_GROUPS = 4
  const int q0 = blockIdx.y * 64;
  const int t = threadIdx.x, w = t >> 6, lane = t & 63;
  const int quad = lane >> 4, c = lane & 15;
  const int myq = q0 + w * 16 + c;     // the q row this lane owns for softmax

  // Q B-frags (B[n=q][k=d]), held in registers across the whole K loop
  const bf16* qrow = q_r + ((size_t)(b * NH + h) * S_ + myq) * HD;
  bf16x8 qf[4];
#pragma unroll
  for (int kk = 0; kk < 4; ++kk) qf[kk] = *(const bf16x8*)(qrow + quad * 8 + kk * 32);

  float m_i = -1e30f, l_i = 0.f;       // per-lane (row = myq)
  f32x4 o_acc[8];
#pragma unroll
  for (int n = 0; n < 8; ++n) o_acc[n] = (f32x4){0.f, 0.f, 0.f, 0.f};

  const bf16* kb_ptr = k_r + (size_t)(b * NKV + kv) * S_ * HD;
  const bf16* vb_ptr = v_t + (size_t)(b * NKV + kv) * HD * S_;

  const int nch = (q0 + 64) >> 5;
  const int ks_key = t >> 3, ks_doff = (t & 7) * 16;
  const int vs_d = t >> 1, vs_koff = (t & 1) * 16;
  // P-conversion shuffle sources: lane (c,quad) pulls key 8q+j from
  // lane c+32*(quad&1) (j<4) / +16 (j>=4); key-tile select = quad>>1.
  const int src0 = c + 32 * (quad & 1);
  const int src1 = src0 + 16;
  const bool hiTile = (quad & 2) != 0;

  for (int ch = 0; ch < nch; ++ch) {
    const int kb = ch * 32;
    __syncthreads();   // previous chunk's LDS reads done before overwrite
    {
      const bf16* kp = kb_ptr + (size_t)(kb + ks_key) * HD + ks_doff;
      bf16x8 kv0 = *(const bf16x8*)(kp);
      bf16x8 kv1 = *(const bf16x8*)(kp + 8);
      const bf16* vp = vb_ptr + (size_t)vs_d * S_ + kb + vs_koff;
      bf16x8 vv0 = *(const bf16x8*)(vp);
      bf16x8 vv1 = *(const bf16x8*)(vp + 8);
      *(bf16x8*)(Ks + ks_key * SKS + ks_doff) = kv0;
      *(bf16x8*)(Ks + ks_key * SKS + ks_doff + 8) = kv1;
      *(bf16x8*)(Vs + vs_d * SVS + vs_koff) = vv0;
      *(bf16x8*)(Vs + vs_d * SVS + vs_koff + 8) = vv1;
    }
    __syncthreads();

    if (kb <= q0 + w * 16 + 15) {      // wave has at least one unmasked key
      // S^T = K Q^T : two 16(key)x16(q) tiles; A-frag = K rows, B-frag = Q
      f32x4 st0 = (f32x4){0.f, 0.f, 0.f, 0.f};
      f32x4 st1 = (f32x4){0.f, 0.f, 0.f, 0.f};
#pragma unroll
      for (int kk = 0; kk < 4; ++kk) {
        bf16x8 kf0 = *(const bf16x8*)(Ks + c * SKS + quad * 8 + kk * 32);
        bf16x8 kf1 = *(const bf16x8*)(Ks + (16 + c) * SKS + quad * 8 + kk * 32);
        st0 = __builtin_amdgcn_mfma_f32_16x16x32_bf16(kf0, qf[kk], st0, 0, 0, 0);
        st1 = __builtin_amdgcn_mfma_f32_16x16x32_bf16(kf1, qf[kk], st1, 0, 0, 0);
      }

      // masking (keys kb+16*kt+quad*4+r vs row myq)
      float v0[4], v1[4];
      const bool needMask = (kb + 31 > q0 + w * 16);
#pragma unroll
      for (int r = 0; r < 4; ++r) { v0[r] = st0[r]; v1[r] = st1[r]; }
      if (needMask) {
        const int key0 = kb + quad * 4;
#pragma unroll
        for (int r = 0; r < 4; ++r) {
          if (key0 + r > myq) v0[r] = -1e30f;
          if (key0 + 16 + r > myq) v1[r] = -1e30f;
        }
      }

      // softmax for row myq: in-reg over 8 vals + 2 shfl across quads
      float mloc = fmaxf(fmaxf(fmaxf(v0[0], v0[1]), fmaxf(v0[2], v0[3])),
                         fmaxf(fmaxf(v1[0], v1[1]), fmaxf(v1[2], v1[3])));
      mloc = fmaxf(mloc, __shfl_xor(mloc, 16, 64));
      mloc = fmaxf(mloc, __shfl_xor(mloc, 32, 64));
      const float mnew = fmaxf(m_i, mloc);
      float e0[4], e1[4];
      float sum = 0.f;
#pragma unroll
      for (int r = 0; r < 4; ++r) {
        e0[r] = __expf(v0[r] - mnew);
        e1[r] = __expf(v1[r] - mnew);
        sum += e0[r] + e1[r];
      }
      sum += __shfl_xor(sum, 16, 64);
      sum += __shfl_xor(sum, 32, 64);
      const float alpha = __expf(m_i - mnew);
      m_i = mnew;
      l_i = l_i * alpha + sum;

      // pack per-reg bf16 pair {tile0, tile1} and shuffle into A-layout
      u32 pk[4];
#pragma unroll
      for (int r = 0; r < 4; ++r) pk[r] = bf16bits(e0[r]) | (bf16bits(e1[r]) << 16);
      u32 a0[4], a1[4];
#pragma unroll
      for (int r = 0; r < 4; ++r) {
        a0[r] = (u32)__shfl((int)pk[r], src0, 64);
        a1[r] = (u32)__shfl((int)pk[r], src1, 64);
      }
      u32 w0, w1, w2, w3;
      if (hiTile) {
        w0 = (a0[0] >> 16) | (a0[1] & 0xffff0000u);
        w1 = (a0[2] >> 16) | (a0[3] & 0xffff0000u);
        w2 = (a1[0] >> 16) | (a1[1] & 0xffff0000u);
        w3 = (a1[2] >> 16) | (a1[3] & 0xffff0000u);
      } else {
        w0 = (a0[0] & 0xffffu) | (a0[1] << 16);
        w1 = (a0[2] & 0xffffu) | (a0[3] << 16);
        w2 = (a1[0] & 0xffffu) | (a1[1] << 16);
        w3 = (a1[2] & 0xffffu) | (a1[3] << 16);
      }
      bf16x8 pf = __builtin_bit_cast(bf16x8, (u32x4){w0, w1, w2, w3});

      // redistribute alpha to O rows (row = quad*4+r lives at src lane quad*4+r)
      float alpha_o[4];
#pragma unroll
      for (int r = 0; r < 4; ++r) alpha_o[r] = __shfl(alpha, quad * 4 + r, 64);

      // rescale O, then O += P V
#pragma unroll
      for (int n = 0; n < 8; ++n) {
#pragma unroll
        for (int r = 0; r < 4; ++r) o_acc[n][r] *= alpha_o[r];
      }
#pragma unroll
      for (int n = 0; n < 8; ++n) {
        bf16x8 vf = *(const bf16x8*)(Vs + (n * 16 + c) * SVS + quad * 8);
        o_acc[n] = __builtin_amdgcn_mfma_f32_16x16x32_bf16(pf, vf, o_acc[n], 0, 0, 0);
      }
    }
  }

  // epilogue: O /= l (l for row quad*4+r lives at lane quad*4+r), write out
  float l_o[4];
#pragma unroll
  for (int r = 0; r < 4; ++r) l_o[r] = __shfl(l_i, quad * 4 + r, 64);
#pragma unroll
  for (int n = 0; n < 8; ++n)
#pragma unroll
    for (int r = 0; r < 4; ++r) {
      const int row = q0 + w * 16 + quad * 4 + r;
      const float ov = o_acc[n][r] / l_o[r];
      attn_out[((size_t)b * S_ + row) * DM + h * HD + n * 16 + c] = (bf16)ov;
    }
}

// ---------------------------------------------------------------------------
extern "C" void kernel_launch(void* const* d_in, const int* in_sizes, int n_in,
                              void* d_out, int out_size, void* d_ws, size_t ws_size,
                              hipStream_t stream) {
  const float* hidden = (const float*)d_in[0];
  const float* cosT = (const float*)d_in[1];
  const float* sinT = (const float*)d_in[2];
  const float* Wqkv = (const float*)d_in[3];
  const float* Wout = (const float*)d_in[4];
  float* out = (float*)d_out;
  char* ws = (char*)d_ws;

  bf16* WqkvT = (bf16*)(ws + 0);
  bf16* q_r = (bf16*)(ws + 0);
  bf16* k_r = (bf16*)(ws + 33554432);
  bf16* WoutT = (bf16*)(ws + 50331648);
  bf16* h_bf = (bf16*)(ws + 83886080);
  bf16* attn_out = (bf16*)(ws + 83886080);
  bf16* v_t = (bf16*)(ws + 117440512);
  bf16* qkv = (bf16*)d_out;

  static bool attr_set = false;
  if (!attr_set) {
    hipFuncSetAttribute(reinterpret_cast<const void*>(&gemm256_bt<true>),
                        hipFuncAttributeMaxDynamicSharedMemorySize, 131072);
    hipFuncSetAttribute(reinterpret_cast<const void*>(&gemm256_bt<false>),
                        hipFuncAttributeMaxDynamicSharedMemorySize, 131072);
    attr_set = true;
  }

  cast_f32_bf16<<<dim3(16384), dim3(256), 0, stream>>>(hidden, h_bf, B_ * S_ * DM);
  transpose_cast_w<<<dim3(QKV_DIM / 64, DM / 64), dim3(256), 0, stream>>>(Wqkv, WqkvT, DM, QKV_DIM);
  transpose_cast_w<<<dim3(DM / 64, DM / 64), dim3(256), 0, stream>>>(Wout, WoutT, DM, DM);
  gemm256_bt<true><<<dim3((QKV_DIM / 256) * ((B_ * S_) / 256)), dim3(512), 131072, stream>>>(
      h_bf, WqkvT, (void*)qkv, B_ * S_, QKV_DIM, DM);
  rope_kernel<<<dim3(B_ * S_), dim3(128), 0, stream>>>(qkv, cosT, sinT, q_r, k_r);
  transpose_v<<<dim3(S_ / 64, HD / 64, B_ * NKV), dim3(256), 0, stream>>>(qkv, v_t);
  attn_kernel<<<dim3(B_ * NH, S_ / 64), dim3(256), 0, stream>>>(q_r, k_r, v_t, attn_out);
  gemm256_bt<false><<<dim3((DM / 256) * ((B_ * S_) / 256)), dim3(512), 131072, stream>>>(
      attn_out, WoutT, (void*)out, B_ * S_, DM, DM);
}

// Round 2
// 780.631 us; speedup vs baseline: 1.1953x; 1.0340x over previous
//
#include <hip/hip_runtime.h>

// ---------------------------------------------------------------------------
// GQA attention block: QKV proj -> RoPE -> causal GQA flash attention -> out proj
// B=2 S=2048 D=4096 NH=32 NKV=8 HD=128 (QKV_DIM=6144)
// R5: GEMM inner loop re-pipelined. R4's 8-barrier-per-K-tile lockstep exposed
//     the LDS fragment-read drain (~512clk) serially against the MFMA cluster
//     (MfmaUtil 38%). Now: fragment double-buffering across phases (next
//     phase's ds_reads issue during current MFMA; compiler emits counted
//     lgkmcnt), 2 barriers/K-tile (start + mid), provably-race-free stage
//     placement (kh1 stages at tile-start BAR, kh0 stages after mid-BAR),
//     counted vmcnt(4)/tile proving ALL of tile t+1's halves complete while
//     keeping 2 half-tiles in flight, incremental stage pointers (no per-phase
//     address rebuild). Swizzle (verified: 0 bank conflicts) unchanged.
// ---------------------------------------------------------------------------

typedef __bf16 bf16;
typedef bf16 bf16x8 __attribute__((ext_vector_type(8)));
typedef bf16 bf16x4 __attribute__((ext_vector_type(4)));
typedef float f32x4 __attribute__((ext_vector_type(4)));
typedef unsigned int u32;
typedef u32 u32x4 __attribute__((ext_vector_type(4)));

#define B_ 2
#define S_ 2048
#define DM 4096
#define NH 32
#define NKV 8
#define HD 128
#define QKV_DIM 6144

typedef __attribute__((address_space(3))) void lds_void;
typedef const __attribute__((address_space(1))) void glb_void;

__device__ __forceinline__ void gld_lds16(const bf16* g, bf16* l) {
  __builtin_amdgcn_global_load_lds((glb_void*)g, (lds_void*)l, 16, 0, 0);
}

__device__ __forceinline__ u32 bf16bits(float x) {
  union { bf16 h; unsigned short s; } u;
  u.h = (bf16)x;
  return (u32)u.s;
}

// ---------------- cast fp32 -> bf16 (hidden states) ----------------
__global__ __launch_bounds__(256) void cast_f32_bf16(const float* __restrict__ src,
                                                     bf16* __restrict__ dst, int n) {
  int i = (blockIdx.x * 256 + threadIdx.x) * 4;
  float4 v = *(const float4*)(src + i);
  bf16x4 o;
  o[0] = (bf16)v.x; o[1] = (bf16)v.y; o[2] = (bf16)v.z; o[3] = (bf16)v.w;
  *(bf16x4*)(dst + i) = o;
}

// ---------------- transpose + cast weights: W[K][N] f32 -> Wt[N][K] bf16 ----
__global__ __launch_bounds__(256) void transpose_cast_w(const float* __restrict__ W,
                                                        bf16* __restrict__ Wt,
                                                        int K, int N) {
  __shared__ float tile[64][65];
  const int n0 = blockIdx.x * 64, k0 = blockIdx.y * 64;
  const int t = threadIdx.x, j = t & 63, i0 = t >> 6;
  for (int p = 0; p < 16; ++p) {
    int i = i0 + p * 4;
    tile[i][j] = W[(size_t)(k0 + i) * N + n0 + j];
  }
  __syncthreads();
  for (int p = 0; p < 16; ++p) {
    int n = i0 + p * 4;
    Wt[(size_t)(n0 + n) * K + k0 + j] = (bf16)tile[j][n];
  }
}

// ---------------- transpose V out of qkv: v_t[b][kv][d][s] ----------------
__global__ __launch_bounds__(256) void transpose_v(const bf16* __restrict__ qkv,
                                                   bf16* __restrict__ v_t) {
  __shared__ bf16 tile[64][65];
  const int s0 = blockIdx.x * 64;
  const int d0 = blockIdx.y * 64;
  const int bk = blockIdx.z;            // b*8+kv
  const int b = bk >> 3, kv = bk & 7;
  const int t = threadIdx.x, j = t & 63, i0 = t >> 6;
  const bf16* src = qkv + (size_t)b * S_ * QKV_DIM + 5120 + kv * HD;  // v offset 5120
  for (int p = 0; p < 16; ++p) {
    int i = i0 + p * 4;
    tile[i][j] = src[(size_t)(s0 + i) * QKV_DIM + d0 + j];
  }
  __syncthreads();
  bf16* dst = v_t + ((size_t)bk * HD + d0) * S_ + s0;
  for (int p = 0; p < 16; ++p) {
    int dd = i0 + p * 4;
    dst[(size_t)dd * S_ + j] = tile[j][dd];
  }
}

// ---------------- RoPE + repack q,k (q pre-scaled by 1/sqrt(HD)) ----------
__global__ __launch_bounds__(128) void rope_kernel(const bf16* __restrict__ qkv,
                                                   const float* __restrict__ cosT,
                                                   const float* __restrict__ sinT,
                                                   bf16* __restrict__ q_r,
                                                   bf16* __restrict__ k_r) {
  const int bs = blockIdx.x;            // b*S + s
  const int b = bs >> 11, s = bs & 2047;
  const int d = threadIdx.x;            // 0..127
  const float cv = cosT[s * HD + d];
  const float sv = sinT[s * HD + d];
  const bf16* row = qkv + (size_t)bs * QKV_DIM;
  const float scale = 0.08838834764831845f;  // 1/sqrt(128)
  for (int h = 0; h < NH; ++h) {
    float x = (float)row[h * HD + d];
    float xr = (d < 64) ? -(float)row[h * HD + d + 64] : (float)row[h * HD + d - 64];
    q_r[(((size_t)(b * NH + h)) * S_ + s) * HD + d] = (bf16)((x * cv + xr * sv) * scale);
  }
  for (int kv = 0; kv < NKV; ++kv) {
    float x = (float)row[DM + kv * HD + d];
    float xr = (d < 64) ? -(float)row[DM + kv * HD + d + 64] : (float)row[DM + kv * HD + d - 64];
    k_r[(((size_t)(b * NKV + kv)) * S_ + s) * HD + d] = (bf16)(x * cv + xr * sv);
  }
}

// ---------------- GEMM: C[M][N] = A[M][K] * Bt[N][K]^T  (256x256 pipelined) --
// 512 threads = 8 waves (2 Mrows x 4 Ncols), per-wave output 128x64.
// BK=64 as two K-halves; LDS per buffer: A[2 kh][256 rows][32 col bf16] + B
// same = 64 KiB; double-buffered = 128 KiB (dynamic).
// Per K-tile: 2 raw barriers (start + mid). Fragment ds_reads for phase j+1
// issue during phase j's 16-MFMA cluster (compiler emits counted lgkmcnt).
// Staging (WAR provable): kh1-region stages (for t+1) right after tile-start
// BAR (those regions' last reads completed before every wave reached this
// BAR); kh0-region stages (for t+2) right after mid-BAR (kh0 fragments were
// consumed by MFMA before any wave reached mid-BAR). vmcnt(4) at tile end
// retires exactly all of t+1's four halves (RAW provable) while leaving
// t+2-kh0's 4 loads in flight (counted, never drained in main loop).
#define BAR() __builtin_amdgcn_s_barrier()
#define VM4() asm volatile("s_waitcnt vmcnt(4)" ::: "memory")
#define VM0() asm volatile("s_waitcnt vmcnt(0)" ::: "memory")
#define PRIO1() __builtin_amdgcn_s_setprio(1)
#define PRIO0() __builtin_amdgcn_s_setprio(0)

#define MFMA16(AF, BF, MH)                                                           \
  do {                                                                               \
    _Pragma("unroll") for (int mm = 0; mm < 4; ++mm) {                               \
      _Pragma("unroll") for (int nn = 0; nn < 4; ++nn) {                             \
        acc[(MH)*4 + mm][nn] = __builtin_amdgcn_mfma_f32_16x16x32_bf16(              \
            AF[mm], BF[nn], acc[(MH)*4 + mm][nn], 0, 0, 0);                          \
      }                                                                              \
    }                                                                                \
  } while (0)

// One K-tile. P = LDS buffer (literal 0/1). DO_S0: stage t+1's kh1 halves.
// DO_S1: stage t+2's kh0 halves. VMEND: end-of-tile vmcnt.
#define GTILE(P, DO_S0, DO_S1, VMEND)                                                \
  do {                                                                               \
    BAR();                                                                           \
    ldAf(P, 0);                       /* af <- A kh0, rows mh0 */                    \
    ldB0(P);                          /* b0 <- B kh0 */                              \
    if (DO_S0) { stageB(P ^ 1, 1, 96); stageA(P ^ 1, 1, 96); }                       \
    ldAg(P, 0);                       /* ag <- A kh0, rows mh1 */                    \
    ldB1(P);                          /* b1 <- B kh1 */                              \
    PRIO1(); MFMA16(af, b0, 0); PRIO0();                                             \
    ldAf(P, 1);                       /* prefetch kh1 frags under MFMA */            \
    PRIO1(); MFMA16(ag, b0, 1); PRIO0();                                             \
    ldAg(P, 1);                                                                      \
    BAR();                            /* mid: all kh0 reads provably done */         \
    if (DO_S1) { stageA(P, 0, 128); stageB(P, 0, 128); }                             \
    PRIO1(); MFMA16(af, b1, 0); MFMA16(ag, b1, 1); PRIO0();                          \
    VMEND;                                                                           \
  } while (0)

#define ADV()                                                                        \
  do { gA += 64; gA2 += 64; gB += 64; gB2 += 64; } while (0)

template <bool OUT_BF16>
__global__ __launch_bounds__(512, 2) void gemm256_bt(const bf16* __restrict__ A,
                                                     const bf16* __restrict__ Bt,
                                                     void* __restrict__ Cout,
                                                     int M, int N, int K) {
  extern __shared__ char lds[];
  const int NT = K >> 6;                 // K-tiles of 64 (even; K=4096 here)

  // bijective XCD swizzle (both grids are multiples of 8)
  const int nwg = gridDim.x;
  const int cpx = nwg >> 3;
  const int wg = (blockIdx.x & 7) * cpx + (blockIdx.x >> 3);
  const int nbx = N >> 8;
  const int bx = wg % nbx, by = wg / nbx;
  const int m0 = by * 256, n0 = bx * 256;

  const int t = threadIdx.x;
  const int w = t >> 6, lane = t & 63;
  const int wr = w >> 2, wc = w & 3;     // wave grid 2 x 4
  const int quad = lane >> 4, c = lane & 15;

  // swizzled ds_read base offsets (verified R4: 0 bank conflicts)
  const int aOff = (((wr * 128 + c) * 64 + quad * 16) ^ ((c & 8) << 2));
  const int bOff = (((wc * 64 + c) * 64 + quad * 16) ^ ((c & 8) << 2)) + 32768;

  // staging: wave w stages rows 32w..32w+31 of each 256-row K-half; global
  // col-granule pre-swizzled so the linear global_load_lds dest lands swizzled
  const int srow = w * 32 + (lane >> 2);
  const int scol = (((lane & 3) ^ ((lane >> 4) & 2)) << 3);  // elements
  const bf16* gA = A + (size_t)(m0 + srow) * K + scol;
  const bf16* gA2 = gA + (size_t)16 * K;
  const bf16* gB = Bt + (size_t)(n0 + srow) * K + scol;
  const bf16* gB2 = gB + (size_t)16 * K;
  char* ldsw = lds + (w << 11);          // wave's 2 KiB slice within a region

  auto stageA = [&](int P, int kh, int ke) {
    bf16* l = (bf16*)(ldsw + (P << 16) + (kh << 14));
    gld_lds16(gA + ke, l);
    gld_lds16(gA2 + ke, (bf16*)((char*)l + 1024));
  };
  auto stageB = [&](int P, int kh, int ke) {
    bf16* l = (bf16*)(ldsw + (P << 16) + 32768 + (kh << 14));
    gld_lds16(gB + ke, l);
    gld_lds16(gB2 + ke, (bf16*)((char*)l + 1024));
  };

  bf16x8 af[4], ag[4], b0[4], b1[4];
  auto ldAf = [&](int P, int kh) {       // A rows [wr*128, +64)
    const char* base = lds + P * 65536 + kh * 16384 + aOff;
    af[0] = *(const bf16x8*)(base);
    af[1] = *(const bf16x8*)(base + 1024);
    af[2] = *(const bf16x8*)(base + 2048);
    af[3] = *(const bf16x8*)(base + 3072);
  };
  auto ldAg = [&](int P, int kh) {       // A rows [wr*128+64, +64)
    const char* base = lds + P * 65536 + kh * 16384 + 4096 + aOff;
    ag[0] = *(const bf16x8*)(base);
    ag[1] = *(const bf16x8*)(base + 1024);
    ag[2] = *(const bf16x8*)(base + 2048);
    ag[3] = *(const bf16x8*)(base + 3072);
  };
  auto ldB0 = [&](int P) {
    const char* base = lds + P * 65536 + bOff;
    b0[0] = *(const bf16x8*)(base);
    b0[1] = *(const bf16x8*)(base + 1024);
    b0[2] = *(const bf16x8*)(base + 2048);
    b0[3] = *(const bf16x8*)(base + 3072);
  };
  auto ldB1 = [&](int P) {
    const char* base = lds + P * 65536 + 16384 + bOff;
    b1[0] = *(const bf16x8*)(base);
    b1[1] = *(const bf16x8*)(base + 1024);
    b1[2] = *(const bf16x8*)(base + 2048);
    b1[3] = *(const bf16x8*)(base + 3072);
  };

  f32x4 acc[8][4];
#pragma unroll
  for (int i = 0; i < 8; ++i)
#pragma unroll
    for (int j = 0; j < 4; ++j) acc[i][j] = (f32x4){0.f, 0.f, 0.f, 0.f};

  // prologue: tile0 all 4 halves + tile1 kh0 pair; retire tile0's, keep 4 in
  // flight (steady-state depth)
  stageA(0, 0, 0); stageB(0, 0, 0);
  stageA(0, 1, 32); stageB(0, 1, 32);
  stageA(1, 0, 64); stageB(1, 0, 64);
  VM4();

  for (int tt = 0; tt < NT - 2; tt += 2) {
    GTILE(0, 1, 1, VM4()); ADV();
    GTILE(1, 1, 1, VM4()); ADV();
  }
  GTILE(0, 1, 0, VM0());                 // penultimate: stage NT-1's kh1 only
  GTILE(1, 0, 0, (void)0);               // last: no staging

  // epilogue: C write (verified fragment mapping: row=quad*4+r, col=c)
  const int crow = m0 + wr * 128 + quad * 4;
  const int ccol = n0 + wc * 64 + c;
#pragma unroll
  for (int mf = 0; mf < 8; ++mf)
#pragma unroll
    for (int nn = 0; nn < 4; ++nn) {
      const int row = crow + mf * 16;
      const int col = ccol + nn * 16;
      if constexpr (OUT_BF16) {
        bf16* Cp = (bf16*)Cout;
#pragma unroll
        for (int r = 0; r < 4; ++r) Cp[(size_t)(row + r) * N + col] = (bf16)acc[mf][nn][r];
      } else {
        float* Cp = (float*)Cout;
#pragma unroll
        for (int r = 0; r < 4; ++r) Cp[(size_t)(row + r) * N + col] = acc[mf][nn][r];
      }
    }
}

// ---------------- flash attention (causal GQA, transposed-S) ---------------
// grid: (B*NH, S/64). 4 waves/block, wave w owns q rows [q0+16w, q0+16w+16).
// K-chunk = 32 keys. Ks[key][d] (+8 pad), Vs[d][key] (+8 pad).
// S^T = K*Q^T: lane (c,quad) holds 8 scores (2 key-tiles x 4 regs) for the
// single q-row q0+16w+c -> softmax reduces in-register + 2 shfl. P converted
// to MFMA A-layout via 8 bpermutes (packed bf16 pairs), no LDS round-trip.
#define SKS 136
#define SVS 40
__global__ __launch_bounds__(256) void attn_kernel(const bf16* __restrict__ q_r,
                                                   const bf16* __restrict__ k_r,
                                                   const bf16* __restrict__ v_t,
                                                   bf16* __restrict__ attn_out) {
  __shared__ bf16 Ks[32 * SKS];
  __shared__ bf16 Vs[128 * SVS];

  const int bh = blockIdx.x;           // b*NH + h
  const int b = bh >> 5, h = bh & 31;
  const int kv = h >> 2;               // N_GROUPS = 4
  const int q0 = blockIdx.y * 64;
  const int t = threadIdx.x, w = t >> 6, lane = t & 63;
  const int quad = lane >> 4, c = lane & 15;
  const int myq = q0 + w * 16 + c;     // the q row this lane owns for softmax

  // Q B-frags (B[n=q][k=d]), held in registers across the whole K loop
  const bf16* qrow = q_r + ((size_t)(b * NH + h) * S_ + myq) * HD;
  bf16x8 qf[4];
#pragma unroll
  for (int kk = 0; kk < 4; ++kk) qf[kk] = *(const bf16x8*)(qrow + quad * 8 + kk * 32);

  float m_i = -1e30f, l_i = 0.f;       // per-lane (row = myq)
  f32x4 o_acc[8];
#pragma unroll
  for (int n = 0; n < 8; ++n) o_acc[n] = (f32x4){0.f, 0.f, 0.f, 0.f};

  const bf16* kb_ptr = k_r + (size_t)(b * NKV + kv) * S_ * HD;
  const bf16* vb_ptr = v_t + (size_t)(b * NKV + kv) * HD * S_;

  const int nch = (q0 + 64) >> 5;
  const int ks_key = t >> 3, ks_doff = (t & 7) * 16;
  const int vs_d = t >> 1, vs_koff = (t & 1) * 16;
  // P-conversion shuffle sources: lane (c,quad) pulls key 8q+j from
  // lane c+32*(quad&1) (j<4) / +16 (j>=4); key-tile select = quad>>1.
  const int src0 = c + 32 * (quad & 1);
  const int src1 = src0 + 16;
  const bool hiTile = (quad & 2) != 0;

  for (int ch = 0; ch < nch; ++ch) {
    const int kb = ch * 32;
    __syncthreads();   // previous chunk's LDS reads done before overwrite
    {
      const bf16* kp = kb_ptr + (size_t)(kb + ks_key) * HD + ks_doff;
      bf16x8 kv0 = *(const bf16x8*)(kp);
      bf16x8 kv1 = *(const bf16x8*)(kp + 8);
      const bf16* vp = vb_ptr + (size_t)vs_d * S_ + kb + vs_koff;
      bf16x8 vv0 = *(const bf16x8*)(vp);
      bf16x8 vv1 = *(const bf16x8*)(vp + 8);
      *(bf16x8*)(Ks + ks_key * SKS + ks_doff) = kv0;
      *(bf16x8*)(Ks + ks_key * SKS + ks_doff + 8) = kv1;
      *(bf16x8*)(Vs + vs_d * SVS + vs_koff) = vv0;
      *(bf16x8*)(Vs + vs_d * SVS + vs_koff + 8) = vv1;
    }
    __syncthreads();

    if (kb <= q0 + w * 16 + 15) {      // wave has at least one unmasked key
      // S^T = K Q^T : two 16(key)x16(q) tiles; A-frag = K rows, B-frag = Q
      f32x4 st0 = (f32x4){0.f, 0.f, 0.f, 0.f};
      f32x4 st1 = (f32x4){0.f, 0.f, 0.f, 0.f};
#pragma unroll
      for (int kk = 0; kk < 4; ++kk) {
        bf16x8 kf0 = *(const bf16x8*)(Ks + c * SKS + quad * 8 + kk * 32);
        bf16x8 kf1 = *(const bf16x8*)(Ks + (16 + c) * SKS + quad * 8 + kk * 32);
        st0 = __builtin_amdgcn_mfma_f32_16x16x32_bf16(kf0, qf[kk], st0, 0, 0, 0);
        st1 = __builtin_amdgcn_mfma_f32_16x16x32_bf16(kf1, qf[kk], st1, 0, 0, 0);
      }

      // masking (keys kb+16*kt+quad*4+r vs row myq)
      float v0[4], v1[4];
      const bool needMask = (kb + 31 > q0 + w * 16);
#pragma unroll
      for (int r = 0; r < 4; ++r) { v0[r] = st0[r]; v1[r] = st1[r]; }
      if (needMask) {
        const int key0 = kb + quad * 4;
#pragma unroll
        for (int r = 0; r < 4; ++r) {
          if (key0 + r > myq) v0[r] = -1e30f;
          if (key0 + 16 + r > myq) v1[r] = -1e30f;
        }
      }

      // softmax for row myq: in-reg over 8 vals + 2 shfl across quads
      float mloc = fmaxf(fmaxf(fmaxf(v0[0], v0[1]), fmaxf(v0[2], v0[3])),
                         fmaxf(fmaxf(v1[0], v1[1]), fmaxf(v1[2], v1[3])));
      mloc = fmaxf(mloc, __shfl_xor(mloc, 16, 64));
      mloc = fmaxf(mloc, __shfl_xor(mloc, 32, 64));
      const float mnew = fmaxf(m_i, mloc);
      float e0[4], e1[4];
      float sum = 0.f;
#pragma unroll
      for (int r = 0; r < 4; ++r) {
        e0[r] = __expf(v0[r] - mnew);
        e1[r] = __expf(v1[r] - mnew);
        sum += e0[r] + e1[r];
      }
      sum += __shfl_xor(sum, 16, 64);
      sum += __shfl_xor(sum, 32, 64);
      const float alpha = __expf(m_i - mnew);
      m_i = mnew;
      l_i = l_i * alpha + sum;

      // pack per-reg bf16 pair {tile0, tile1} and shuffle into A-layout
      u32 pk[4];
#pragma unroll
      for (int r = 0; r < 4; ++r) pk[r] = bf16bits(e0[r]) | (bf16bits(e1[r]) << 16);
      u32 a0[4], a1[4];
#pragma unroll
      for (int r = 0; r < 4; ++r) {
        a0[r] = (u32)__shfl((int)pk[r], src0, 64);
        a1[r] = (u32)__shfl((int)pk[r], src1, 64);
      }
      u32 w0, w1, w2, w3;
      if (hiTile) {
        w0 = (a0[0] >> 16) | (a0[1] & 0xffff0000u);
        w1 = (a0[2] >> 16) | (a0[3] & 0xffff0000u);
        w2 = (a1[0] >> 16) | (a1[1] & 0xffff0000u);
        w3 = (a1[2] >> 16) | (a1[3] & 0xffff0000u);
      } else {
        w0 = (a0[0] & 0xffffu) | (a0[1] << 16);
        w1 = (a0[2] & 0xffffu) | (a0[3] << 16);
        w2 = (a1[0] & 0xffffu) | (a1[1] << 16);
        w3 = (a1[2] & 0xffffu) | (a1[3] << 16);
      }
      bf16x8 pf = __builtin_bit_cast(bf16x8, (u32x4){w0, w1, w2, w3});

      // redistribute alpha to O rows (row = quad*4+r lives at src lane quad*4+r)
      float alpha_o[4];
#pragma unroll
      for (int r = 0; r < 4; ++r) alpha_o[r] = __shfl(alpha, quad * 4 + r, 64);

      // rescale O, then O += P V
#pragma unroll
      for (int n = 0; n < 8; ++n) {
#pragma unroll
        for (int r = 0; r < 4; ++r) o_acc[n][r] *= alpha_o[r];
      }
#pragma unroll
      for (int n = 0; n < 8; ++n) {
        bf16x8 vf = *(const bf16x8*)(Vs + (n * 16 + c) * SVS + quad * 8);
        o_acc[n] = __builtin_amdgcn_mfma_f32_16x16x32_bf16(pf, vf, o_acc[n], 0, 0, 0);
      }
    }
  }

  // epilogue: O /= l (l for row quad*4+r lives at lane quad*4+r), write out
  float l_o[4];
#pragma unroll
  for (int r = 0; r < 4; ++r) l_o[r] = __shfl(l_i, quad * 4 + r, 64);
#pragma unroll
  for (int n = 0; n < 8; ++n)
#pragma unroll
    for (int r = 0; r < 4; ++r) {
      const int row = q0 + w * 16 + quad * 4 + r;
      const float ov = o_acc[n][r] / l_o[r];
      attn_out[((size_t)b * S_ + row) * DM + h * HD + n * 16 + c] = (bf16)ov;
    }
}

// ---------------------------------------------------------------------------
extern "C" void kernel_launch(void* const* d_in, const int* in_sizes, int n_in,
                              void* d_out, int out_size, void* d_ws, size_t ws_size,
                              hipStream_t stream) {
  const float* hidden = (const float*)d_in[0];
  const float* cosT = (const float*)d_in[1];
  const float* sinT = (const float*)d_in[2];
  const float* Wqkv = (const float*)d_in[3];
  const float* Wout = (const float*)d_in[4];
  float* out = (float*)d_out;
  char* ws = (char*)d_ws;

  bf16* WqkvT = (bf16*)(ws + 0);
  bf16* q_r = (bf16*)(ws + 0);
  bf16* k_r = (bf16*)(ws + 33554432);
  bf16* WoutT = (bf16*)(ws + 50331648);
  bf16* h_bf = (bf16*)(ws + 83886080);
  bf16* attn_out = (bf16*)(ws + 83886080);
  bf16* v_t = (bf16*)(ws + 117440512);
  bf16* qkv = (bf16*)d_out;

  static bool attr_set = false;
  if (!attr_set) {
    hipFuncSetAttribute(reinterpret_cast<const void*>(&gemm256_bt<true>),
                        hipFuncAttributeMaxDynamicSharedMemorySize, 131072);
    hipFuncSetAttribute(reinterpret_cast<const void*>(&gemm256_bt<false>),
                        hipFuncAttributeMaxDynamicSharedMemorySize, 131072);
    attr_set = true;
  }

  cast_f32_bf16<<<dim3(16384), dim3(256), 0, stream>>>(hidden, h_bf, B_ * S_ * DM);
  transpose_cast_w<<<dim3(QKV_DIM / 64, DM / 64), dim3(256), 0, stream>>>(Wqkv, WqkvT, DM, QKV_DIM);
  transpose_cast_w<<<dim3(DM / 64, DM / 64), dim3(256), 0, stream>>>(Wout, WoutT, DM, DM);
  gemm256_bt<true><<<dim3((QKV_DIM / 256) * ((B_ * S_) / 256)), dim3(512), 131072, stream>>>(
      h_bf, WqkvT, (void*)qkv, B_ * S_, QKV_DIM, DM);
  rope_kernel<<<dim3(B_ * S_), dim3(128), 0, stream>>>(qkv, cosT, sinT, q_r, k_r);
  transpose_v<<<dim3(S_ / 64, HD / 64, B_ * NKV), dim3(256), 0, stream>>>(qkv, v_t);
  attn_kernel<<<dim3(B_ * NH, S_ / 64), dim3(256), 0, stream>>>(q_r, k_r, v_t, attn_out);
  gemm256_bt<false><<<dim3((DM / 256) * ((B_ * S_) / 256)), dim3(512), 131072, stream>>>(
      attn_out, WoutT, (void*)out, B_ * S_, DM, DM);
}